// Round 12
// baseline (162.366 us; speedup 1.0000x reference)
//
#include <hip/hip_runtime.h>

namespace {
constexpr int BATCH = 512;
constexpr int SEQL  = 512;
constexpr int HID   = 256;
constexpr int MORPH = 24;
constexpr float NEGV = -1.0e9f;
constexpr int NTHR  = 1024;
}

typedef float f4 __attribute__((ext_vector_type(4)));

__device__ __forceinline__ unsigned okey(float f) {
    unsigned u = __float_as_uint(f);
    return u ^ (unsigned)(((int)u >> 31) | 0x80000000);
}

// One block per b; 1024 thr = 16 waves, 2 blocks/CU.
// P1: wave w reads rows [32w,32w+32) ONCE; per-lane f4 slice accumulates 8
//     register chunk-sums (4 rows each) while scores come from a 64-lane
//     shuffle-reduced dot. Data is read from HBM exactly once.
// P2: radix select -> c2m (unchanged).
// P3: chunk flush: whole chunks -> 4 LDS atomics; separator-broken chunks
//     (~24/block) re-read <=4 rows from L2/L3. menc re-read drops 137->~49 MB.
// P4: menc + bpm writes (NT).
extern "C" __global__ __launch_bounds__(NTHR)
void morphseg_fused(const float* __restrict__ we,    // [B, L, H]
                    const int*   __restrict__ wlen,  // [B]
                    const int*   __restrict__ nmorph,// [B]
                    const float* __restrict__ Wv,    // [H]
                    const float* __restrict__ bias,  // [1]
                    float* __restrict__ out)         // menc [B*M*H] then bpm [B*L*M]
{
    const int b    = blockIdx.x;
    const int tid  = threadIdx.x;
    const int lane = tid & 63;
    const int wave = tid >> 6;

    __shared__ unsigned s_keys[SEQL];                // 2 KB
    __shared__ int s_hist[256];                      // 1 KB
    __shared__ int s_c2m[SEQL];                      // 2 KB
    __shared__ float s_acc[MORPH][HID];              // 24 KB
    __shared__ unsigned long long s_eqm[8], s_ind[8];
    __shared__ unsigned s_p, s_T;
    __shared__ int s_Kr, s_KrF, s_done;

    const int wl = wlen[b];
    const int nm = nmorph[b];
    const int K  = nm - 1;
    const float b0 = bias[0];
    const float* __restrict__ werow = we + (size_t)b * (SEQL * HID);
    const unsigned KEYNEG = okey(NEGV);

    // ---- init
    if (tid < SEQL) s_keys[tid] = KEYNEG;
    {
        float* af = &s_acc[0][0];
        for (int i = tid; i < MORPH * HID; i += NTHR) af[i] = 0.0f;
    }
    if (tid == 0) { s_p = 0u; s_Kr = K; s_done = 0; }
    __syncthreads();

    // ---- Phase 1: single read of rows; register chunk sums + scores
    const f4 wv = reinterpret_cast<const f4*>(Wv)[lane];   // floats 4l..4l+3
    f4 ca0 = {0,0,0,0}, ca1 = {0,0,0,0}, ca2 = {0,0,0,0}, ca3 = {0,0,0,0};
    f4 ca4 = {0,0,0,0}, ca5 = {0,0,0,0}, ca6 = {0,0,0,0}, ca7 = {0,0,0,0};
    {
        const int r0 = wave * 32;
        #pragma unroll
        for (int j = 0; j < 32; ++j) {
            const int row = r0 + j;
            if (row < wl) {                    // wave-uniform
                const f4 v = reinterpret_cast<const f4*>(werow + (size_t)row * HID)[lane];
                switch (j >> 2) {              // compile-time per unrolled j
                    case 0: ca0 += v; break;  case 1: ca1 += v; break;
                    case 2: ca2 += v; break;  case 3: ca3 += v; break;
                    case 4: ca4 += v; break;  case 5: ca5 += v; break;
                    case 6: ca6 += v; break;  case 7: ca7 += v; break;
                }
                float d = v.x * wv.x;
                d = fmaf(v.y, wv.y, d); d = fmaf(v.z, wv.z, d); d = fmaf(v.w, wv.w, d);
                #pragma unroll
                for (int off = 1; off < 64; off <<= 1)
                    d += __shfl_xor(d, off, 64);
                if (lane == 0 && row < wl - 1) s_keys[row] = okey(d + b0);
            }
        }
    }
    __syncthreads();

    // ---- Phase 2: radix select, MSB-first, early exit on exact boundary
    int done = 0;
    for (int pass = 0; pass < 4 && !done; ++pass) {
        const int shift = 24 - 8 * pass;
        if (tid < 256) s_hist[tid] = 0;
        __syncthreads();
        if (tid < SEQL) {
            const unsigned k = s_keys[tid];
            if (pass == 0 || (k >> (shift + 8)) == (s_p >> (shift + 8)))
                atomicAdd(&s_hist[(k >> shift) & 255], 1);
        }
        __syncthreads();
        if (wave == 0) {
            const int v0 = lane * 4;
            const int h0 = s_hist[v0], h1 = s_hist[v0 + 1];
            const int h2 = s_hist[v0 + 2], h3 = s_hist[v0 + 3];
            const int local = h0 + h1 + h2 + h3;
            int T = local;
            #pragma unroll
            for (int off = 1; off < 64; off <<= 1) {
                const int u = __shfl_down(T, off, 64);
                if (lane + off < 64) T += u;
            }
            const int A  = T - local;
            const int S3 = A + h3, S2 = S3 + h2, S1 = S2 + h1, S0 = S1 + h0;
            const int Kr = s_Kr;
            const unsigned p = s_p;
            int v = -1, Sv = 0, Sv1 = 0;
            if (A  < Kr && Kr <= S3) { v = v0 + 3; Sv = S3; Sv1 = A;  }
            if (S3 < Kr && Kr <= S2) { v = v0 + 2; Sv = S2; Sv1 = S3; }
            if (S2 < Kr && Kr <= S1) { v = v0 + 1; Sv = S1; Sv1 = S2; }
            if (S1 < Kr && Kr <= S0) { v = v0 + 0; Sv = S0; Sv1 = S1; }
            if (v >= 0) {
                const unsigned pv = p | ((unsigned)v << shift);
                if (Sv == Kr)        { s_T = pv - 1u; s_KrF = 0;        s_done = 1; }
                else if (shift == 0) { s_T = pv;      s_KrF = Kr - Sv1; s_done = 1; }
                else                 { s_p = pv;      s_Kr = Kr - Sv1; }
            }
        }
        __syncthreads();
        done = s_done;
    }

    // ---- separator flags (stable ties) -> c2m
    const unsigned Tf = s_T;
    const int KrF = s_KrF;
    const unsigned k = (tid < SEQL) ? s_keys[tid] : 0u;
    const bool gt = (tid < SEQL) && (k > Tf);
    const bool eq = (tid < SEQL) && (k == Tf);
    const unsigned long long eb = __ballot(eq);
    if (lane == 0 && wave < 8) s_eqm[wave] = eb;
    __syncthreads();

    auto prefix8 = [&](const unsigned long long* w8, int pos) -> int {
        const int wi = pos >> 6;
        const unsigned long long lowmask = (1ull << (pos & 63)) - 1ull;
        int r = 0;
        #pragma unroll
        for (int q2 = 0; q2 < 8; ++q2) {
            const unsigned long long w = w8[q2];
            r += (q2 < wi) ? __popcll(w) : ((q2 == wi) ? __popcll(w & lowmask) : 0);
        }
        return r;
    };

    int f = 0;
    if (tid < SEQL) f = gt || (eq && prefix8(s_eqm, tid) < KrF);
    const unsigned long long fb = __ballot(f);
    if (lane == 0 && wave < 8) s_ind[wave] = fb;
    __syncthreads();
    if (tid < SEQL) s_c2m[tid] = prefix8(s_ind, tid);
    __syncthreads();

    // ---- Phase 3: chunk flush (register sums -> s_acc)
    {
        const int base = lane * 4;
        #pragma unroll
        for (int c8 = 0; c8 < 8; ++c8) {
            const int r0 = wave * 32 + c8 * 4;
            if (r0 < wl) {                      // wave-uniform
                const int rend = (r0 + 4 < wl) ? (r0 + 4) : wl;
                const int m0 = s_c2m[r0];
                const int m1 = s_c2m[rend - 1];
                if (m0 == m1 && rend == r0 + 4) {
                    f4 ca;
                    switch (c8) {
                        case 0: ca = ca0; break;  case 1: ca = ca1; break;
                        case 2: ca = ca2; break;  case 3: ca = ca3; break;
                        case 4: ca = ca4; break;  case 5: ca = ca5; break;
                        case 6: ca = ca6; break;  default: ca = ca7; break;
                    }
                    atomicAdd(&s_acc[m0][base + 0], ca.x);
                    atomicAdd(&s_acc[m0][base + 1], ca.y);
                    atomicAdd(&s_acc[m0][base + 2], ca.z);
                    atomicAdd(&s_acc[m0][base + 3], ca.w);
                } else {
                    for (int r = r0; r < rend; ++r) {
                        const f4 v = reinterpret_cast<const f4*>(werow + (size_t)r * HID)[lane];
                        const int mm = s_c2m[r];
                        atomicAdd(&s_acc[mm][base + 0], v.x);
                        atomicAdd(&s_acc[mm][base + 1], v.y);
                        atomicAdd(&s_acc[mm][base + 2], v.z);
                        atomicAdd(&s_acc[mm][base + 3], v.w);
                    }
                }
            }
        }
    }
    __syncthreads();

    // ---- Phase 4: menc + bpm writes (NT)
    {
        float* __restrict__ mout = out + (size_t)b * (MORPH * HID);
        const f4* af = reinterpret_cast<const f4*>(&s_acc[0][0]);
        for (int i = tid; i < MORPH * HID / 4; i += NTHR)
            __builtin_nontemporal_store(af[i], reinterpret_cast<f4*>(mout) + i);
    }
    {
        float* __restrict__ bpm = out + (size_t)BATCH * MORPH * HID + (size_t)b * (SEQL * MORPH);
        for (int v = tid; v < SEQL * MORPH / 4; v += NTHR) {
            const int l  = v / 6;
            const int qv = v - l * 6;
            const int c  = s_c2m[l];
            const int mb = qv * 4;
            const bool valid = (l < wl);
            f4 o;
            o.x = (valid && c == mb + 0 && mb + 0 < nm) ? 1.0f : 0.0f;
            o.y = (valid && c == mb + 1 && mb + 1 < nm) ? 1.0f : 0.0f;
            o.z = (valid && c == mb + 2 && mb + 2 < nm) ? 1.0f : 0.0f;
            o.w = (valid && c == mb + 3 && mb + 3 < nm) ? 1.0f : 0.0f;
            __builtin_nontemporal_store(o, reinterpret_cast<f4*>(bpm) + v);
        }
    }
}

extern "C" void kernel_launch(void* const* d_in, const int* in_sizes, int n_in,
                              void* d_out, int out_size, void* d_ws, size_t ws_size,
                              hipStream_t stream) {
    const float* we     = (const float*)d_in[0];
    const int*   wlen   = (const int*)d_in[1];
    const int*   nmorph = (const int*)d_in[2];
    const float* Wv     = (const float*)d_in[3];
    const float* bias   = (const float*)d_in[4];
    float* out = (float*)d_out;

    morphseg_fused<<<dim3(BATCH), dim3(NTHR), 0, stream>>>(
        we, wlen, nmorph, Wv, bias, out);
}

// Round 13
// 130.802 us; speedup vs baseline: 1.2413x; 1.2413x over previous
//
#include <hip/hip_runtime.h>

namespace {
constexpr int BATCH = 512;
constexpr int SEQL  = 512;
constexpr int HID   = 256;
constexpr int MORPH = 24;
constexpr float NEGV = -1.0e9f;
constexpr int NTHR  = 1024;
}

typedef float f4 __attribute__((ext_vector_type(4)));

__device__ __forceinline__ unsigned okey(float f) {
    unsigned u = __float_as_uint(f);
    return u ^ (unsigned)(((int)u >> 31) | 0x80000000);
}

// One block per b; 1024 thr = 16 waves, 2 blocks/CU (VGPR capped at 64).
// P1: wave w reads rows [32w,32w+32) ONCE. Per-lane f4 slice accumulates into
//     4 NAMED register chunk-sums (8 rows each; all indexing static), scores
//     via interleaved 6-step shuffle reduces (4 chains in flight).
// P2: radix select -> c2m (monotone).
// P3: run-length flush: uniform full chunks consume the register sum; broken
//     chunks (~23/block) re-read <=8 rows from L3. Re-read 137 -> ~49 MB.
// P4: menc + bpm writes (NT).
extern "C" __global__ __launch_bounds__(NTHR, 8)
void morphseg_fused(const float* __restrict__ we,    // [B, L, H]
                    const int*   __restrict__ wlen,  // [B]
                    const int*   __restrict__ nmorph,// [B]
                    const float* __restrict__ Wv,    // [H]
                    const float* __restrict__ bias,  // [1]
                    float* __restrict__ out)         // menc [B*M*H] then bpm [B*L*M]
{
    const int b    = blockIdx.x;
    const int tid  = threadIdx.x;
    const int lane = tid & 63;
    const int wave = tid >> 6;

    __shared__ unsigned s_keys[SEQL];                // 2 KB
    __shared__ int s_hist[256];                      // 1 KB
    __shared__ int s_c2m[SEQL];                      // 2 KB
    __shared__ float s_acc[MORPH][HID];              // 24 KB
    __shared__ unsigned long long s_eqm[8], s_ind[8];
    __shared__ unsigned s_p, s_T;
    __shared__ int s_Kr, s_KrF, s_done;

    const int wl = wlen[b];
    const int nm = nmorph[b];
    const int K  = nm - 1;
    const float b0 = bias[0];
    const float* __restrict__ werow = we + (size_t)b * (SEQL * HID);
    const unsigned KEYNEG = okey(NEGV);

    // ---- init
    if (tid < SEQL) s_keys[tid] = KEYNEG;
    {
        float* af = &s_acc[0][0];
        for (int i = tid; i < MORPH * HID; i += NTHR) af[i] = 0.0f;
    }
    if (tid == 0) { s_p = 0u; s_Kr = K; s_done = 0; }
    __syncthreads();

    // ---- Phase 1: single read; 4 named 8-row chunk accs + scores
    const f4 wv = reinterpret_cast<const f4*>(Wv)[lane];   // floats 4l..4l+3
    const int wbase = wave * 32;
    f4 cacc0 = {0,0,0,0}, cacc1 = {0,0,0,0}, cacc2 = {0,0,0,0}, cacc3 = {0,0,0,0};

    auto ldrow = [&](int r) -> f4 {
        f4 z = {0.f, 0.f, 0.f, 0.f};
        if (r < wl)    // wave-uniform
            z = reinterpret_cast<const f4*>(werow + (size_t)r * HID)[lane];
        return z;
    };

#define GROUP(g, ACC) { \
    const int r0 = wbase + (g) * 4; \
    f4 v0 = ldrow(r0 + 0), v1 = ldrow(r0 + 1); \
    f4 v2 = ldrow(r0 + 2), v3 = ldrow(r0 + 3); \
    ACC += v0; ACC += v1; ACC += v2; ACC += v3; \
    float d0 = v0.x * wv.x; d0 = fmaf(v0.y, wv.y, d0); d0 = fmaf(v0.z, wv.z, d0); d0 = fmaf(v0.w, wv.w, d0); \
    float d1 = v1.x * wv.x; d1 = fmaf(v1.y, wv.y, d1); d1 = fmaf(v1.z, wv.z, d1); d1 = fmaf(v1.w, wv.w, d1); \
    float d2 = v2.x * wv.x; d2 = fmaf(v2.y, wv.y, d2); d2 = fmaf(v2.z, wv.z, d2); d2 = fmaf(v2.w, wv.w, d2); \
    float d3 = v3.x * wv.x; d3 = fmaf(v3.y, wv.y, d3); d3 = fmaf(v3.z, wv.z, d3); d3 = fmaf(v3.w, wv.w, d3); \
    _Pragma("unroll") \
    for (int off = 1; off < 64; off <<= 1) { \
        d0 += __shfl_xor(d0, off, 64); \
        d1 += __shfl_xor(d1, off, 64); \
        d2 += __shfl_xor(d2, off, 64); \
        d3 += __shfl_xor(d3, off, 64); \
    } \
    if (lane == 0) { \
        if (r0 + 0 < wl - 1) s_keys[r0 + 0] = okey(d0 + b0); \
        if (r0 + 1 < wl - 1) s_keys[r0 + 1] = okey(d1 + b0); \
        if (r0 + 2 < wl - 1) s_keys[r0 + 2] = okey(d2 + b0); \
        if (r0 + 3 < wl - 1) s_keys[r0 + 3] = okey(d3 + b0); \
    } \
}
    GROUP(0, cacc0) GROUP(1, cacc0)
    GROUP(2, cacc1) GROUP(3, cacc1)
    GROUP(4, cacc2) GROUP(5, cacc2)
    GROUP(6, cacc3) GROUP(7, cacc3)
#undef GROUP
    __syncthreads();

    // ---- Phase 2: radix select, MSB-first, early exit on exact boundary
    int done = 0;
    for (int pass = 0; pass < 4 && !done; ++pass) {
        const int shift = 24 - 8 * pass;
        if (tid < 256) s_hist[tid] = 0;
        __syncthreads();
        if (tid < SEQL) {
            const unsigned k = s_keys[tid];
            if (pass == 0 || (k >> (shift + 8)) == (s_p >> (shift + 8)))
                atomicAdd(&s_hist[(k >> shift) & 255], 1);
        }
        __syncthreads();
        if (wave == 0) {
            const int v0 = lane * 4;
            const int h0 = s_hist[v0], h1 = s_hist[v0 + 1];
            const int h2 = s_hist[v0 + 2], h3 = s_hist[v0 + 3];
            const int local = h0 + h1 + h2 + h3;
            int T = local;
            #pragma unroll
            for (int off = 1; off < 64; off <<= 1) {
                const int u = __shfl_down(T, off, 64);
                if (lane + off < 64) T += u;
            }
            const int A  = T - local;
            const int S3 = A + h3, S2 = S3 + h2, S1 = S2 + h1, S0 = S1 + h0;
            const int Kr = s_Kr;
            const unsigned p = s_p;
            int v = -1, Sv = 0, Sv1 = 0;
            if (A  < Kr && Kr <= S3) { v = v0 + 3; Sv = S3; Sv1 = A;  }
            if (S3 < Kr && Kr <= S2) { v = v0 + 2; Sv = S2; Sv1 = S3; }
            if (S2 < Kr && Kr <= S1) { v = v0 + 1; Sv = S1; Sv1 = S2; }
            if (S1 < Kr && Kr <= S0) { v = v0 + 0; Sv = S0; Sv1 = S1; }
            if (v >= 0) {
                const unsigned pv = p | ((unsigned)v << shift);
                if (Sv == Kr)        { s_T = pv - 1u; s_KrF = 0;        s_done = 1; }
                else if (shift == 0) { s_T = pv;      s_KrF = Kr - Sv1; s_done = 1; }
                else                 { s_p = pv;      s_Kr = Kr - Sv1; }
            }
        }
        __syncthreads();
        done = s_done;
    }

    // ---- separator flags (stable ties) -> c2m
    const unsigned Tf = s_T;
    const int KrF = s_KrF;
    const unsigned k = (tid < SEQL) ? s_keys[tid] : 0u;
    const bool gt = (tid < SEQL) && (k > Tf);
    const bool eq = (tid < SEQL) && (k == Tf);
    const unsigned long long eb = __ballot(eq);
    if (lane == 0 && wave < 8) s_eqm[wave] = eb;
    __syncthreads();

    auto prefix8 = [&](const unsigned long long* w8, int pos) -> int {
        const int wi = pos >> 6;
        const unsigned long long lowmask = (1ull << (pos & 63)) - 1ull;
        int r = 0;
        #pragma unroll
        for (int q2 = 0; q2 < 8; ++q2) {
            const unsigned long long w = w8[q2];
            r += (q2 < wi) ? __popcll(w) : ((q2 == wi) ? __popcll(w & lowmask) : 0);
        }
        return r;
    };

    int f = 0;
    if (tid < SEQL) f = gt || (eq && prefix8(s_eqm, tid) < KrF);
    const unsigned long long fb = __ballot(f);
    if (lane == 0 && wave < 8) s_ind[wave] = fb;
    __syncthreads();
    if (tid < SEQL) s_c2m[tid] = prefix8(s_ind, tid);
    __syncthreads();

    // ---- Phase 3: run-length flush of chunk sums (c2m monotone)
    {
        const int base = lane * 4;
        f4 racc = {0,0,0,0};
        int mcur = -1;
#define FLUSH() { if (mcur >= 0) { \
        atomicAdd(&s_acc[mcur][base + 0], racc.x); \
        atomicAdd(&s_acc[mcur][base + 1], racc.y); \
        atomicAdd(&s_acc[mcur][base + 2], racc.z); \
        atomicAdd(&s_acc[mcur][base + 3], racc.w); \
        racc.x = racc.y = racc.z = racc.w = 0.f; } }
#define CHUNK(c, CACC) { \
    const int r0 = wbase + (c) * 8; \
    if (r0 < wl) { \
        const bool full = (r0 + 8 <= wl); \
        const int rend = full ? r0 + 8 : wl; \
        const int m0 = s_c2m[r0]; \
        const int m1 = s_c2m[rend - 1]; \
        if (full && m0 == m1) { \
            if (m0 != mcur) { FLUSH(); mcur = m0; } \
            racc += CACC; \
        } else { \
            for (int r = r0; r < rend; ++r) { \
                const int mm = s_c2m[r]; \
                if (mm != mcur) { FLUSH(); mcur = mm; } \
                racc += reinterpret_cast<const f4*>(werow + (size_t)r * HID)[lane]; \
            } \
        } \
    } \
}
        CHUNK(0, cacc0) CHUNK(1, cacc1) CHUNK(2, cacc2) CHUNK(3, cacc3)
        FLUSH();
#undef CHUNK
#undef FLUSH
    }
    __syncthreads();

    // ---- Phase 4: menc + bpm writes (NT)
    {
        float* __restrict__ mout = out + (size_t)b * (MORPH * HID);
        const f4* af = reinterpret_cast<const f4*>(&s_acc[0][0]);
        for (int i = tid; i < MORPH * HID / 4; i += NTHR)
            __builtin_nontemporal_store(af[i], reinterpret_cast<f4*>(mout) + i);
    }
    {
        float* __restrict__ bpm = out + (size_t)BATCH * MORPH * HID + (size_t)b * (SEQL * MORPH);
        for (int v = tid; v < SEQL * MORPH / 4; v += NTHR) {
            const int l  = v / 6;
            const int qv = v - l * 6;
            const int c  = s_c2m[l];
            const int mb = qv * 4;
            const bool valid = (l < wl);
            f4 o;
            o.x = (valid && c == mb + 0 && mb + 0 < nm) ? 1.0f : 0.0f;
            o.y = (valid && c == mb + 1 && mb + 1 < nm) ? 1.0f : 0.0f;
            o.z = (valid && c == mb + 2 && mb + 2 < nm) ? 1.0f : 0.0f;
            o.w = (valid && c == mb + 3 && mb + 3 < nm) ? 1.0f : 0.0f;
            __builtin_nontemporal_store(o, reinterpret_cast<f4*>(bpm) + v);
        }
    }
}

extern "C" void kernel_launch(void* const* d_in, const int* in_sizes, int n_in,
                              void* d_out, int out_size, void* d_ws, size_t ws_size,
                              hipStream_t stream) {
    const float* we     = (const float*)d_in[0];
    const int*   wlen   = (const int*)d_in[1];
    const int*   nmorph = (const int*)d_in[2];
    const float* Wv     = (const float*)d_in[3];
    const float* bias   = (const float*)d_in[4];
    float* out = (float*)d_out;

    morphseg_fused<<<dim3(BATCH), dim3(NTHR), 0, stream>>>(
        we, wlen, nmorph, Wv, bias, out);
}

// Round 14
// 62.834 us; speedup vs baseline: 2.5840x; 2.0817x over previous
//
#include <hip/hip_runtime.h>

namespace {
constexpr int BATCH = 512;
constexpr int SEQL  = 512;
constexpr int HID   = 256;
constexpr int MORPH = 24;
constexpr float NEGV = -1.0e9f;
constexpr int NTHR  = 512;    // 8 waves -> ~5.5 KB LDS -> 4 blocks/CU co-resident
constexpr int NWAVE = 8;
}

typedef float f4 __attribute__((ext_vector_type(4)));

__device__ __forceinline__ unsigned okey(float f) {
    unsigned u = __float_as_uint(f);
    return u ^ (unsigned)(((int)u >> 31) | 0x80000000);
}

// One block per b; 512 thr = 8 waves; 4 blocks/CU (wave-capped) so blocks at
// different phases overlap HBM-read / VALU / write streams via the scheduler.
// P1: keys (4 rows/wave/iter, 16-lane row slices). P2: radix select -> c2m+sep.
// P3: menc wave-per-morpheme (register acc, exclusive NT stores, no LDS acc).
// P4: bpm one-hot (NT stores).
extern "C" __global__ __launch_bounds__(NTHR)
void morphseg_kernel(const float* __restrict__ we,    // [B, L, H]
                     const int*   __restrict__ wlen,  // [B]
                     const int*   __restrict__ nmorph,// [B]
                     const float* __restrict__ Wv,    // [H]
                     const float* __restrict__ bias,  // [1]
                     float* __restrict__ out)         // menc [B*M*H] then bpm [B*L*M]
{
    const int b    = blockIdx.x;
    const int tid  = threadIdx.x;
    const int lane = tid & 63;
    const int wave = tid >> 6;

    __shared__ unsigned s_keys[SEQL];                // 2 KB
    __shared__ int s_hist[256];                      // 1 KB
    __shared__ int s_c2m[SEQL];                      // 2 KB
    __shared__ int s_sep[32];
    __shared__ unsigned long long s_eqm[8], s_ind[8];
    __shared__ unsigned s_p, s_T;
    __shared__ int s_Kr, s_KrF, s_done;

    const int wl = wlen[b];
    const int nm = nmorph[b];
    const int K  = nm - 1;
    const float b0 = bias[0];
    const float* __restrict__ werow = we + (size_t)b * (SEQL * HID);
    const unsigned KEYNEG = okey(NEGV);

    // ---- init
    s_keys[tid] = KEYNEG;          // NTHR == SEQL
    if (tid == 0) { s_p = 0u; s_Kr = K; s_done = 0; }
    __syncthreads();

    // ---- Phase 1: keys. 4 rows per wave per iter; lane = 16*rg + hg.
    {
        const int hg = lane & 15;          // h-slice: floats [hg*16, hg*16+16)
        const int rg = lane >> 4;          // row within the 4-row group
        const f4* __restrict__ W4 = reinterpret_cast<const f4*>(Wv);
        const f4 w0 = W4[hg * 4 + 0], w1 = W4[hg * 4 + 1];
        const f4 w2 = W4[hg * 4 + 2], w3 = W4[hg * 4 + 3];
        const int nvalid = wl - 1;
        for (int l0 = wave * 4; l0 < nvalid; l0 += NWAVE * 4) {
            const int row = l0 + rg;
            if (row < nvalid) {            // uniform per 16-lane group
                const f4* __restrict__ rp =
                    reinterpret_cast<const f4*>(werow + (size_t)row * HID);
                const f4 v0 = rp[hg * 4 + 0], v1 = rp[hg * 4 + 1];
                const f4 v2 = rp[hg * 4 + 2], v3 = rp[hg * 4 + 3];
                const f4 p = v0 * w0 + v1 * w1 + v2 * w2 + v3 * w3;
                float d = (p[0] + p[1]) + (p[2] + p[3]);
                #pragma unroll
                for (int off = 1; off < 16; off <<= 1)
                    d += __shfl_xor(d, off, 64);
                if (hg == 0) s_keys[row] = okey(d + b0);
            }
        }
    }
    __syncthreads();

    // ---- Phase 2: radix select, MSB-first, early exit on exact boundary
    int done = 0;
    for (int pass = 0; pass < 4 && !done; ++pass) {
        const int shift = 24 - 8 * pass;
        if (tid < 256) s_hist[tid] = 0;
        __syncthreads();
        {
            const unsigned k = s_keys[tid];
            if (pass == 0 || (k >> (shift + 8)) == (s_p >> (shift + 8)))
                atomicAdd(&s_hist[(k >> shift) & 255], 1);
        }
        __syncthreads();
        if (wave == 0) {
            const int v0 = lane * 4;
            const int h0 = s_hist[v0], h1 = s_hist[v0 + 1];
            const int h2 = s_hist[v0 + 2], h3 = s_hist[v0 + 3];
            const int local = h0 + h1 + h2 + h3;
            int T = local;
            #pragma unroll
            for (int off = 1; off < 64; off <<= 1) {
                const int u = __shfl_down(T, off, 64);
                if (lane + off < 64) T += u;
            }
            const int A  = T - local;
            const int S3 = A + h3, S2 = S3 + h2, S1 = S2 + h1, S0 = S1 + h0;
            const int Kr = s_Kr;
            const unsigned p = s_p;
            int v = -1, Sv = 0, Sv1 = 0;
            if (A  < Kr && Kr <= S3) { v = v0 + 3; Sv = S3; Sv1 = A;  }
            if (S3 < Kr && Kr <= S2) { v = v0 + 2; Sv = S2; Sv1 = S3; }
            if (S2 < Kr && Kr <= S1) { v = v0 + 1; Sv = S1; Sv1 = S2; }
            if (S1 < Kr && Kr <= S0) { v = v0 + 0; Sv = S0; Sv1 = S1; }
            if (v >= 0) {
                const unsigned pv = p | ((unsigned)v << shift);
                if (Sv == Kr)        { s_T = pv - 1u; s_KrF = 0;        s_done = 1; }
                else if (shift == 0) { s_T = pv;      s_KrF = Kr - Sv1; s_done = 1; }
                else                 { s_p = pv;      s_Kr = Kr - Sv1; }
            }
        }
        __syncthreads();
        done = s_done;
    }

    // ---- separator flags (stable ties) -> c2m + sep list
    const unsigned Tf = s_T;
    const int KrF = s_KrF;
    const unsigned k = s_keys[tid];
    const bool gt = (k > Tf);
    const bool eq = (k == Tf);
    const unsigned long long eb = __ballot(eq);
    if (lane == 0) s_eqm[wave] = eb;
    __syncthreads();

    auto prefix8 = [&](const unsigned long long* w8, int pos) -> int {
        const int wi = pos >> 6;
        const unsigned long long lowmask = (1ull << (pos & 63)) - 1ull;
        int r = 0;
        #pragma unroll
        for (int q2 = 0; q2 < 8; ++q2) {
            const unsigned long long w = w8[q2];
            r += (q2 < wi) ? __popcll(w) : ((q2 == wi) ? __popcll(w & lowmask) : 0);
        }
        return r;
    };

    const int f = gt || (eq && prefix8(s_eqm, tid) < KrF);
    const unsigned long long fb = __ballot(f);
    if (lane == 0) s_ind[wave] = fb;
    __syncthreads();
    {
        const int cnt = prefix8(s_ind, tid);
        s_c2m[tid] = cnt;
        if (f) s_sep[cnt] = tid;     // cnt in [0,K): unique per separator
    }
    __syncthreads();

    // ---- Phase 3: menc, wave-per-morpheme (m = wave, wave+8, wave+16)
    for (int m = wave; m < MORPH; m += NWAVE) {
        f4 t = {0.f, 0.f, 0.f, 0.f};
        if (m < nm) {
            const int lo = (m == 0) ? 0 : s_sep[m - 1] + 1;
            const int hi = (m < K) ? s_sep[m] : wl - 1;   // inclusive
            f4 a0 = {0.f,0.f,0.f,0.f}, a1 = {0.f,0.f,0.f,0.f};
            int l = lo;
            for (; l + 1 <= hi; l += 2) {
                a0 += reinterpret_cast<const f4*>(werow + (size_t)(l    ) * HID)[lane];
                a1 += reinterpret_cast<const f4*>(werow + (size_t)(l + 1) * HID)[lane];
            }
            if (l <= hi)
                a0 += reinterpret_cast<const f4*>(werow + (size_t)l * HID)[lane];
            t = a0 + a1;
        }
        __builtin_nontemporal_store(
            t, reinterpret_cast<f4*>(out + (size_t)b * (MORPH * HID) + (size_t)m * HID) + lane);
    }

    // ---- Phase 4: bpm one-hot, float4 (6 per l-row), NT stores
    {
        float* __restrict__ bpm = out + (size_t)BATCH * MORPH * HID + (size_t)b * (SEQL * MORPH);
        for (int v = tid; v < SEQL * MORPH / 4; v += NTHR) {
            const int l  = v / 6;
            const int qv = v - l * 6;
            const int c  = s_c2m[l];
            const int mb = qv * 4;
            const bool valid = (l < wl);
            f4 o;
            o.x = (valid && c == mb + 0 && mb + 0 < nm) ? 1.0f : 0.0f;
            o.y = (valid && c == mb + 1 && mb + 1 < nm) ? 1.0f : 0.0f;
            o.z = (valid && c == mb + 2 && mb + 2 < nm) ? 1.0f : 0.0f;
            o.w = (valid && c == mb + 3 && mb + 3 < nm) ? 1.0f : 0.0f;
            __builtin_nontemporal_store(o, reinterpret_cast<f4*>(bpm) + v);
        }
    }
}

extern "C" void kernel_launch(void* const* d_in, const int* in_sizes, int n_in,
                              void* d_out, int out_size, void* d_ws, size_t ws_size,
                              hipStream_t stream) {
    const float* we     = (const float*)d_in[0];
    const int*   wlen   = (const int*)d_in[1];
    const int*   nmorph = (const int*)d_in[2];
    const float* Wv     = (const float*)d_in[3];
    const float* bias   = (const float*)d_in[4];
    float* out = (float*)d_out;

    morphseg_kernel<<<dim3(BATCH), dim3(NTHR), 0, stream>>>(
        we, wlen, nmorph, Wv, bias, out);
}

// Round 15
// 55.342 us; speedup vs baseline: 2.9339x; 1.1354x over previous
//
#include <hip/hip_runtime.h>

namespace {
constexpr int BATCH = 512;
constexpr int SEQL  = 512;
constexpr int HID   = 256;
constexpr int MORPH = 24;
constexpr float NEGV = -1.0e9f;
constexpr int NTHR  = 512;    // 8 waves; ~5.5 KB LDS
constexpr int NWAVE = 8;
}

typedef float f4 __attribute__((ext_vector_type(4)));

__device__ __forceinline__ unsigned okey(float f) {
    unsigned u = __float_as_uint(f);
    return u ^ (unsigned)(((int)u >> 31) | 0x80000000);
}

// One block per b; 512 thr = 8 waves.
// P1: keys (4 rows/wave/iter, 16-lane row slices). P2: radix select -> c2m+sep.
// P3: bpm one-hot FIRST (dependency-free NT store stream drains under P4's
//     load latency). P4: menc wave-per-morpheme with 4 accumulator chains.
extern "C" __global__ __launch_bounds__(NTHR)
void morphseg_kernel(const float* __restrict__ we,    // [B, L, H]
                     const int*   __restrict__ wlen,  // [B]
                     const int*   __restrict__ nmorph,// [B]
                     const float* __restrict__ Wv,    // [H]
                     const float* __restrict__ bias,  // [1]
                     float* __restrict__ out)         // menc [B*M*H] then bpm [B*L*M]
{
    const int b    = blockIdx.x;
    const int tid  = threadIdx.x;
    const int lane = tid & 63;
    const int wave = tid >> 6;

    __shared__ unsigned s_keys[SEQL];                // 2 KB
    __shared__ int s_hist[256];                      // 1 KB
    __shared__ int s_c2m[SEQL];                      // 2 KB
    __shared__ int s_sep[32];
    __shared__ unsigned long long s_eqm[8], s_ind[8];
    __shared__ unsigned s_p, s_T;
    __shared__ int s_Kr, s_KrF, s_done;

    const int wl = wlen[b];
    const int nm = nmorph[b];
    const int K  = nm - 1;
    const float b0 = bias[0];
    const float* __restrict__ werow = we + (size_t)b * (SEQL * HID);
    const unsigned KEYNEG = okey(NEGV);

    // ---- init
    s_keys[tid] = KEYNEG;          // NTHR == SEQL
    if (tid == 0) { s_p = 0u; s_Kr = K; s_done = 0; }
    __syncthreads();

    // ---- Phase 1: keys. 4 rows per wave per iter; lane = 16*rg + hg.
    {
        const int hg = lane & 15;          // h-slice: floats [hg*16, hg*16+16)
        const int rg = lane >> 4;          // row within the 4-row group
        const f4* __restrict__ W4 = reinterpret_cast<const f4*>(Wv);
        const f4 w0 = W4[hg * 4 + 0], w1 = W4[hg * 4 + 1];
        const f4 w2 = W4[hg * 4 + 2], w3 = W4[hg * 4 + 3];
        const int nvalid = wl - 1;
        for (int l0 = wave * 4; l0 < nvalid; l0 += NWAVE * 4) {
            const int row = l0 + rg;
            if (row < nvalid) {            // uniform per 16-lane group
                const f4* __restrict__ rp =
                    reinterpret_cast<const f4*>(werow + (size_t)row * HID);
                const f4 v0 = rp[hg * 4 + 0], v1 = rp[hg * 4 + 1];
                const f4 v2 = rp[hg * 4 + 2], v3 = rp[hg * 4 + 3];
                const f4 p = v0 * w0 + v1 * w1 + v2 * w2 + v3 * w3;
                float d = (p[0] + p[1]) + (p[2] + p[3]);
                #pragma unroll
                for (int off = 1; off < 16; off <<= 1)
                    d += __shfl_xor(d, off, 64);
                if (hg == 0) s_keys[row] = okey(d + b0);
            }
        }
    }
    __syncthreads();

    // ---- Phase 2: radix select, MSB-first, early exit on exact boundary
    int done = 0;
    for (int pass = 0; pass < 4 && !done; ++pass) {
        const int shift = 24 - 8 * pass;
        if (tid < 256) s_hist[tid] = 0;
        __syncthreads();
        {
            const unsigned k = s_keys[tid];
            if (pass == 0 || (k >> (shift + 8)) == (s_p >> (shift + 8)))
                atomicAdd(&s_hist[(k >> shift) & 255], 1);
        }
        __syncthreads();
        if (wave == 0) {
            const int v0 = lane * 4;
            const int h0 = s_hist[v0], h1 = s_hist[v0 + 1];
            const int h2 = s_hist[v0 + 2], h3 = s_hist[v0 + 3];
            const int local = h0 + h1 + h2 + h3;
            int T = local;
            #pragma unroll
            for (int off = 1; off < 64; off <<= 1) {
                const int u = __shfl_down(T, off, 64);
                if (lane + off < 64) T += u;
            }
            const int A  = T - local;
            const int S3 = A + h3, S2 = S3 + h2, S1 = S2 + h1, S0 = S1 + h0;
            const int Kr = s_Kr;
            const unsigned p = s_p;
            int v = -1, Sv = 0, Sv1 = 0;
            if (A  < Kr && Kr <= S3) { v = v0 + 3; Sv = S3; Sv1 = A;  }
            if (S3 < Kr && Kr <= S2) { v = v0 + 2; Sv = S2; Sv1 = S3; }
            if (S2 < Kr && Kr <= S1) { v = v0 + 1; Sv = S1; Sv1 = S2; }
            if (S1 < Kr && Kr <= S0) { v = v0 + 0; Sv = S0; Sv1 = S1; }
            if (v >= 0) {
                const unsigned pv = p | ((unsigned)v << shift);
                if (Sv == Kr)        { s_T = pv - 1u; s_KrF = 0;        s_done = 1; }
                else if (shift == 0) { s_T = pv;      s_KrF = Kr - Sv1; s_done = 1; }
                else                 { s_p = pv;      s_Kr = Kr - Sv1; }
            }
        }
        __syncthreads();
        done = s_done;
    }

    // ---- separator flags (stable ties) -> c2m + sep list
    const unsigned Tf = s_T;
    const int KrF = s_KrF;
    const unsigned k = s_keys[tid];
    const bool gt = (k > Tf);
    const bool eq = (k == Tf);
    const unsigned long long eb = __ballot(eq);
    if (lane == 0) s_eqm[wave] = eb;
    __syncthreads();

    auto prefix8 = [&](const unsigned long long* w8, int pos) -> int {
        const int wi = pos >> 6;
        const unsigned long long lowmask = (1ull << (pos & 63)) - 1ull;
        int r = 0;
        #pragma unroll
        for (int q2 = 0; q2 < 8; ++q2) {
            const unsigned long long w = w8[q2];
            r += (q2 < wi) ? __popcll(w) : ((q2 == wi) ? __popcll(w & lowmask) : 0);
        }
        return r;
    };

    const int f = gt || (eq && prefix8(s_eqm, tid) < KrF);
    const unsigned long long fb = __ballot(f);
    if (lane == 0) s_ind[wave] = fb;
    __syncthreads();
    {
        const int cnt = prefix8(s_ind, tid);
        s_c2m[tid] = cnt;
        if (f) s_sep[cnt] = tid;     // cnt in [0,K): unique per separator
    }
    __syncthreads();

    // ---- Phase 3: bpm one-hot FIRST (pure store stream, no load deps)
    {
        float* __restrict__ bpm = out + (size_t)BATCH * MORPH * HID + (size_t)b * (SEQL * MORPH);
        for (int v = tid; v < SEQL * MORPH / 4; v += NTHR) {
            const int l  = v / 6;
            const int qv = v - l * 6;
            const int c  = s_c2m[l];
            const int mb = qv * 4;
            const bool valid = (l < wl);
            f4 o;
            o.x = (valid && c == mb + 0 && mb + 0 < nm) ? 1.0f : 0.0f;
            o.y = (valid && c == mb + 1 && mb + 1 < nm) ? 1.0f : 0.0f;
            o.z = (valid && c == mb + 2 && mb + 2 < nm) ? 1.0f : 0.0f;
            o.w = (valid && c == mb + 3 && mb + 3 < nm) ? 1.0f : 0.0f;
            __builtin_nontemporal_store(o, reinterpret_cast<f4*>(bpm) + v);
        }
    }

    // ---- Phase 4: menc, wave-per-morpheme, 4 independent chains
    for (int m = wave; m < MORPH; m += NWAVE) {
        f4 t = {0.f, 0.f, 0.f, 0.f};
        if (m < nm) {
            const int lo = (m == 0) ? 0 : s_sep[m - 1] + 1;
            const int hi = (m < K) ? s_sep[m] : wl - 1;   // inclusive
            f4 a0 = {0.f,0.f,0.f,0.f}, a1 = {0.f,0.f,0.f,0.f};
            f4 a2 = {0.f,0.f,0.f,0.f}, a3 = {0.f,0.f,0.f,0.f};
            int l = lo;
            for (; l + 3 <= hi; l += 4) {
                a0 += reinterpret_cast<const f4*>(werow + (size_t)(l    ) * HID)[lane];
                a1 += reinterpret_cast<const f4*>(werow + (size_t)(l + 1) * HID)[lane];
                a2 += reinterpret_cast<const f4*>(werow + (size_t)(l + 2) * HID)[lane];
                a3 += reinterpret_cast<const f4*>(werow + (size_t)(l + 3) * HID)[lane];
            }
            for (; l <= hi; ++l)
                a0 += reinterpret_cast<const f4*>(werow + (size_t)l * HID)[lane];
            t = (a0 + a1) + (a2 + a3);
        }
        __builtin_nontemporal_store(
            t, reinterpret_cast<f4*>(out + (size_t)b * (MORPH * HID) + (size_t)m * HID) + lane);
    }
}

extern "C" void kernel_launch(void* const* d_in, const int* in_sizes, int n_in,
                              void* d_out, int out_size, void* d_ws, size_t ws_size,
                              hipStream_t stream) {
    const float* we     = (const float*)d_in[0];
    const int*   wlen   = (const int*)d_in[1];
    const int*   nmorph = (const int*)d_in[2];
    const float* Wv     = (const float*)d_in[3];
    const float* bias   = (const float*)d_in[4];
    float* out = (float*)d_out;

    morphseg_kernel<<<dim3(BATCH), dim3(NTHR), 0, stream>>>(
        we, wlen, nmorph, Wv, bias, out);
}